// Round 9
// baseline (395.503 us; speedup 1.0000x reference)
//
#include <hip/hip_runtime.h>
#include <math.h>

#define NP 50000
#define CH 64
#define KMAX 64
#define KNN 16
#define NB 25
#define PTS (NP / NB)            // 2000
#define EPSF 1e-16f
#define NTILES (NP / 16)         // 3125 (16-node tiles for qkv)
#define OCTS (NP / 4)            // attn processes 4 nodes/block (r6 structure)
#define L2E 1.4426950408889634f
#define LN2 0.6931471805599453f
#define PPB 8                    // pool partials per cloud
#define PROWS (PTS / PPB)        // 250
#define TPB 4                    // qkv tiles per block

typedef __attribute__((ext_vector_type(8))) short short8;
typedef __attribute__((ext_vector_type(4))) float float4v;
typedef __attribute__((ext_vector_type(4))) unsigned int uint4v;
typedef __attribute__((ext_vector_type(2))) unsigned int uint2v;
typedef __attribute__((ext_vector_type(4))) unsigned short ushort4v;

__device__ __forceinline__ ushort f2b(float f) {
  unsigned u = __float_as_uint(f);
  unsigned r = (u + 0x7FFFu + ((u >> 16) & 1u)) >> 16;
  return (ushort)r;
}
__device__ __forceinline__ float b2f(ushort h) {
  return __uint_as_float(((unsigned)h) << 16);
}

// ws layout (bytes):
//   qbf  : 3 * NP * CH * 2   (bf16, log2e-scaled Q)
//   kvp  : 3 * NP * CH * 4   (packed dword: K_s bf16 hi | V bf16 lo)
//   wpack: 36864 ushort (A-frag layout; Q,K pre-scaled by log2e)
//   poolP: NB * PPB * CH fp32 (per-cloud pool partials)
#define QBF_BYTES   ((size_t)3 * NP * CH * 2)
#define KVP_BYTES   ((size_t)3 * NP * CH * 4)
#define WPACK_ELEMS (9 * 4 * 2 * 64 * 8)

// ---------------------------------------------------------------------------
// Kernel 0: prep = pool partials (blocks 0..NB*PPB-1) + W pack (A-frag).
// ---------------------------------------------------------------------------
__global__ __launch_bounds__(256) void prep_kernel(
    const float* __restrict__ x,
    const float* __restrict__ Wv,
    const float* __restrict__ Wq,
    const float* __restrict__ Wk,
    ushort* __restrict__ wpack,
    float* __restrict__ poolP) {
  const int tid = threadIdx.x;
  const int bid = blockIdx.x;
  __shared__ float red[4][CH];

  if (bid < NB * PPB) {                 // ---- pool partial path ----
    const int lane = tid & 63;
    const int wave = tid >> 6;
    const int cloud = bid >> 3;
    const int part  = bid & 7;
    const float* xb = x + ((size_t)cloud * PTS + part * PROWS) * CH;
    float m0 = -INFINITY, m1 = -INFINITY;
    for (int r = wave * 2; r < PROWS; r += 8) {
      m0 = fmaxf(m0, xb[(size_t)(r + 0) * CH + lane]);
      m1 = fmaxf(m1, xb[(size_t)(r + 1) * CH + lane]);
    }
    red[wave][lane] = fmaxf(m0, m1);
    __syncthreads();
    if (wave == 0) {
      poolP[(size_t)bid * CH + lane] = fmaxf(fmaxf(red[0][lane], red[1][lane]),
                                             fmaxf(red[2][lane], red[3][lane]));
    }
  } else {                              // ---- W pack path ----
    int pid = (bid - NB * PPB) * 256 + tid;
    if (pid < WPACK_ELEMS) {
      int j     = pid & 7;
      int lane  = (pid >> 3) & 63;
      int kstep = (pid >> 9) & 1;
      int mtile = (pid >> 10) & 3;
      int mat   = pid >> 12;
      const float* W;
      int d;
      float scale;
      if (mat < 3)      { W = Wq; d = mat;     scale = L2E; }
      else if (mat < 6) { W = Wk; d = mat - 3; scale = L2E; }
      else              { W = Wv; d = mat - 6; scale = 1.f; }
      int oc = mtile * 16 + (lane & 15);
      int ic = kstep * 32 + ((lane >> 4) & 3) * 8 + j;
      wpack[pid] = f2b(W[d * CH * CH + ic * CH + oc] * scale);
    }
  }
}

// ---------------------------------------------------------------------------
// Kernel 1: fused x->bf16 conversion + QKV MFMA. Block (64,6), 4 tiles:
// stage 64 nodes of x into LDS as bf16 (padded node stride 72 ushorts ->
// conflict-free frag reads), then wave wy computes slice wy (0-2: Q_dd,
// 3-5: KV_dd packed) for all 4 tiles with resident A-frags.
// ---------------------------------------------------------------------------
__global__ __launch_bounds__(384, 2) void qkv_fused(
    const float* __restrict__ x,
    const ushort* __restrict__ wpack,
    ushort* __restrict__ qbf,
    unsigned int* __restrict__ kvp) {
  const int t0 = blockIdx.x * TPB;
  const int count = (NTILES - t0 < TPB) ? (NTILES - t0) : TPB;
  const int tid = threadIdx.y * 64 + threadIdx.x;

  __shared__ ushort xs[TPB][16][72];       // node stride 144B (bank-padded)

  // stage: each thread converts float4 -> ushort4 (x is node-major, CH=64)
  for (int g = tid; g < count * 256; g += 384) {
    float4 v = ((const float4*)x)[(size_t)t0 * 256 + g];
    int tile = g >> 8;
    int rem  = g & 255;
    int node = rem >> 4;
    int c4   = rem & 15;
    ushort4v o;
    o[0] = f2b(v.x); o[1] = f2b(v.y); o[2] = f2b(v.z); o[3] = f2b(v.w);
    *(ushort4v*)&xs[tile][node][c4 * 4] = o;
  }
  __syncthreads();

  const int lane = threadIdx.x;
  const int y    = threadIdx.y;            // slice
  const int kbase = (lane >> 4) * 8;
  const int nl    = lane & 15;

  if (y < 3) {                             // ---- Q slice ----
    const int dd = y;
    short8 af[4][2];
#pragma unroll
    for (int mt = 0; mt < 4; ++mt)
#pragma unroll
      for (int ks = 0; ks < 2; ++ks)
        af[mt][ks] = *(const short8*)(wpack +
            ((((size_t)dd * 4 + mt) * 2 + ks) * 64 + lane) * 8);
    ushort* outQ = qbf + (size_t)dd * NP * CH;
    for (int t = 0; t < count; ++t) {
      short8 b0 = *(const short8*)&xs[t][nl][kbase];
      short8 b1 = *(const short8*)&xs[t][nl][kbase + 32];
      int myNode = (t0 + t) * 16 + nl;
#pragma unroll
      for (int mt = 0; mt < 4; ++mt) {
        float4v acc = {0.f, 0.f, 0.f, 0.f};
        acc = __builtin_amdgcn_mfma_f32_16x16x32_bf16(af[mt][0], b0, acc, 0, 0, 0);
        acc = __builtin_amdgcn_mfma_f32_16x16x32_bf16(af[mt][1], b1, acc, 0, 0, 0);
        int oc = mt * 16 + (lane >> 4) * 4;
        uint2v o;
        o[0] = (unsigned)f2b(acc[0]) | ((unsigned)f2b(acc[1]) << 16);
        o[1] = (unsigned)f2b(acc[2]) | ((unsigned)f2b(acc[3]) << 16);
        *(uint2v*)(outQ + (size_t)myNode * CH + oc) = o;
      }
    }
  } else {                                 // ---- KV packed slice ----
    const int dd = y - 3;
    short8 afK[4][2], afV[4][2];
#pragma unroll
    for (int mt = 0; mt < 4; ++mt)
#pragma unroll
      for (int ks = 0; ks < 2; ++ks) {
        afK[mt][ks] = *(const short8*)(wpack +
            ((((size_t)(3 + dd) * 4 + mt) * 2 + ks) * 64 + lane) * 8);
        afV[mt][ks] = *(const short8*)(wpack +
            ((((size_t)(6 + dd) * 4 + mt) * 2 + ks) * 64 + lane) * 8);
      }
    unsigned int* outKV = kvp + (size_t)dd * NP * CH;
    for (int t = 0; t < count; ++t) {
      short8 b0 = *(const short8*)&xs[t][nl][kbase];
      short8 b1 = *(const short8*)&xs[t][nl][kbase + 32];
      int myNode = (t0 + t) * 16 + nl;
#pragma unroll
      for (int mt = 0; mt < 4; ++mt) {
        float4v aK = {0.f, 0.f, 0.f, 0.f};
        float4v aV = {0.f, 0.f, 0.f, 0.f};
        aK = __builtin_amdgcn_mfma_f32_16x16x32_bf16(afK[mt][0], b0, aK, 0, 0, 0);
        aK = __builtin_amdgcn_mfma_f32_16x16x32_bf16(afK[mt][1], b1, aK, 0, 0, 0);
        aV = __builtin_amdgcn_mfma_f32_16x16x32_bf16(afV[mt][0], b0, aV, 0, 0, 0);
        aV = __builtin_amdgcn_mfma_f32_16x16x32_bf16(afV[mt][1], b1, aV, 0, 0, 0);
        int oc = mt * 16 + (lane >> 4) * 4;
        uint4v o;
#pragma unroll
        for (int i = 0; i < 4; ++i)
          o[i] = ((unsigned)f2b(aK[i]) << 16) | (unsigned)f2b(aV[i]);
        *(uint4v*)(outKV + (size_t)myNode * CH + oc) = o;
      }
    }
  }
}

// ---------------------------------------------------------------------------
// Kernel 2: fused attention (r6 structure). Block (64,6): 4 nodes; wave
// wy = (dd, half), 8 edges, single stream (no spill). Edge loop in two
// 4-slot batches with w-reads + all 4 gathers hoisted ahead of the math.
// K used unmasked from the packed dword (~bf16-ulp perturbation, r7/r8).
// Partials {s, P=accv-q*s} via padded LDS; wave 0 combines.
// ---------------------------------------------------------------------------
__global__ __launch_bounds__(384, 6) void attn_kernel(
    const float* __restrict__ x,
    const float* __restrict__ pos,
    const float* __restrict__ Wp,
    const float* __restrict__ bp,
    const int*   __restrict__ edge_src,
    const ushort* __restrict__ qbf,
    const unsigned int* __restrict__ kvp,
    const float* __restrict__ poolP,
    float* __restrict__ out) {
  const int bx  = blockIdx.x;
  const int xcd = bx & 7;
  const int kk  = bx >> 3;
  const int base = (OCTS * xcd) >> 3;
  const int cnt  = ((OCTS * (xcd + 1)) >> 3) - base;
  if (kk >= cnt) return;                    // whole-block uniform
  const int node0 = (base + kk) * 4;

  const int wy   = threadIdx.y;             // 0..5
  const int dd   = wy % 3;                  // wave-uniform dilation
  const int half = wy / 3;                  // 0 or 1 (edge half)
  const int tid  = wy * 64 + threadIdx.x;

  __shared__ float sEdge[4 * 260];          // [nl][p] {relx,rely,relz,rowOfs}
  __shared__ float sS[6 * 4 * 68];          // [wy][nl][ch] partial s
  __shared__ float sP[6 * 4 * 68];          // [wy][nl][ch] partial accv-q*s

  if (tid < 256) {
    int nl = tid >> 6, p = tid & 63;
    int nd = node0 + nl;
    int j = edge_src[(size_t)nd * KMAX + p];
    float4v w;
    w[0] = pos[nd * 3 + 0] - pos[j * 3 + 0];
    w[1] = pos[nd * 3 + 1] - pos[j * 3 + 1];
    w[2] = pos[nd * 3 + 2] - pos[j * 3 + 2];
    w[3] = __int_as_float(j << 8);          // byte offset of packed-KV row
    *(float4v*)&sEdge[nl * 260 + p * 4] = w;
  }
  __syncthreads();

  const int lane = threadIdx.x;
  const int g    = lane >> 4;
  const int cl   = lane & 15;
  const int node = node0 + g;
  const unsigned clOfs = (unsigned)(cl << 4);

  float4v bq, bpv, wp0, wp1, wp2;
  {
    ushort4v qh = *(const ushort4v*)(qbf + ((size_t)dd * NP + node) * CH + cl * 4);
    const float* WpD = Wp + dd * 192;
    wp0 = *(const float4v*)(WpD + 0 * 64 + cl * 4) * L2E;
    wp1 = *(const float4v*)(WpD + 1 * 64 + cl * 4) * L2E;
    wp2 = *(const float4v*)(WpD + 2 * 64 + cl * 4) * L2E;
    bpv = *(const float4v*)(bp + dd * 64 + cl * 4) * L2E;
#pragma unroll
    for (int i = 0; i < 4; ++i) bq[i] = b2f(qh[i]) + bpv[i];
  }
  const char* KVb = (const char*)(kvp + (size_t)dd * NP * CH);

  const float* sMy = &sEdge[g * 260] + (((half * 8) << dd) * 4);
  const int estp = (1 << dd) * 4;           // floats per edge step

  float4v s    = {0.f, 0.f, 0.f, 0.f};
  float4v accv = {0.f, 0.f, 0.f, 0.f};
#pragma unroll
  for (int b4 = 0; b4 < 2; ++b4) {
    float4v w4[4];
    uint4v  u4[4];
#pragma unroll
    for (int j = 0; j < 4; ++j)
      w4[j] = *(const float4v*)(sMy + (b4 * 4 + j) * estp);
#pragma unroll
    for (int j = 0; j < 4; ++j)
      u4[j] = *(const uint4v*)(KVb + (__float_as_uint(w4[j][3]) + clOfs));
#pragma unroll
    for (int j = 0; j < 4; ++j) {
      float4v t = bq + w4[j][0] * wp0 + w4[j][1] * wp1 + w4[j][2] * wp2;
      float4v wgt, vf;
#pragma unroll
      for (int i = 0; i < 4; ++i) {
        // unmasked K: low16 bits are V's -> <=0.4% relative perturbation
        wgt[i] = __builtin_amdgcn_exp2f(t[i] - __uint_as_float(u4[j][i]));
        vf[i]  = __uint_as_float(u4[j][i] << 16);
      }
      s += wgt;
#pragma unroll
      for (int i = 0; i < 4; ++i)
        accv[i] = fmaf(wgt[i], fmaf(LN2, t[i], vf[i]), accv[i]);
    }
  }

  // publish partials: P = accv - q*s  (q = (bq - bp_s)*ln2, uniform per node)
  {
    float4v qo;
#pragma unroll
    for (int i = 0; i < 4; ++i) qo[i] = (bq[i] - bpv[i]) * LN2;
    *(float4v*)&sS[(wy * 4 + g) * 68 + cl * 4] = s;
    *(float4v*)&sP[(wy * 4 + g) * 68 + cl * 4] = accv - qo * s;
  }
  __syncthreads();

  if (wy == 0) {                            // single combine wave
    float4v res;
#pragma unroll
    for (int d2 = 0; d2 < 3; ++d2) {
      float4v s0 = *(const float4v*)&sS[((d2    ) * 4 + g) * 68 + cl * 4];
      float4v s1 = *(const float4v*)&sS[((d2 + 3) * 4 + g) * 68 + cl * 4];
      float4v p0 = *(const float4v*)&sP[((d2    ) * 4 + g) * 68 + cl * 4];
      float4v p1 = *(const float4v*)&sP[((d2 + 3) * 4 + g) * 68 + cl * 4];
      float4v st = s0 + s1;
      float4v pt = p0 + p1;
      float4v r;
#pragma unroll
      for (int i = 0; i < 4; ++i)
        r[i] = pt[i] * __builtin_amdgcn_rcpf(st[i] + EPSF);
      if (d2 == 0) res = r;
      else {
#pragma unroll
        for (int i = 0; i < 4; ++i) res[i] = fmaxf(res[i], r[i]);
      }
    }
    const int b = node / PTS;
    const float* pp = poolP + (size_t)(b * PPB) * CH + cl * 4;
    float4v pv = *(const float4v*)pp;
#pragma unroll
    for (int q2 = 1; q2 < PPB; ++q2) {
      float4v t2 = *(const float4v*)(pp + (size_t)q2 * CH);
#pragma unroll
      for (int i = 0; i < 4; ++i) pv[i] = fmaxf(pv[i], t2[i]);
    }
    float4v xv = *(const float4v*)(x + (size_t)node * CH + cl * 4);
#pragma unroll
    for (int i = 0; i < 4; ++i) res[i] = fmaxf(res[i], pv[i]) + xv[i];
    *(float4v*)(out + (size_t)node * CH + cl * 4) = res;
  }
}

// ---------------------------------------------------------------------------
extern "C" void kernel_launch(void* const* d_in, const int* in_sizes, int n_in,
                              void* d_out, int out_size, void* d_ws, size_t ws_size,
                              hipStream_t stream) {
  const float* x    = (const float*)d_in[0];
  const float* pos  = (const float*)d_in[1];
  const float* Wv   = (const float*)d_in[2];
  const float* Wq   = (const float*)d_in[3];
  const float* Wk   = (const float*)d_in[4];
  const float* Wp   = (const float*)d_in[5];
  const float* bp   = (const float*)d_in[6];
  const int*   ei   = (const int*)d_in[7];
  float* out = (float*)d_out;

  char* wsb = (char*)d_ws;
  ushort* qbf   = (ushort*)wsb;
  unsigned int* kvp = (unsigned int*)(wsb + QBF_BYTES);
  ushort* wpack = (ushort*)(wsb + QBF_BYTES + KVP_BYTES);
  float*  poolP = (float*)(wsb + QBF_BYTES + KVP_BYTES + (size_t)WPACK_ELEMS * 2);

  // 0) pool partials + W pack
  {
    int packBlocks = (WPACK_ELEMS + 255) / 256;
    dim3 grid(NB * PPB + packBlocks);
    hipLaunchKernelGGL(prep_kernel, grid, dim3(256), 0, stream,
                       x, Wv, Wq, Wk, wpack, poolP);
  }
  // 1) fused convert + Q/KV MFMA (all slices share staged x)
  {
    dim3 grid((NTILES + TPB - 1) / TPB);
    dim3 block(64, 6);
    hipLaunchKernelGGL(qkv_fused, grid, block, 0, stream, x, wpack, qbf, kvp);
  }
  // 2) fused attention + combine
  {
    dim3 grid(8 * ((OCTS + 7) / 8));
    dim3 block(64, 6);
    hipLaunchKernelGGL(attn_kernel, grid, block, 0, stream,
                       x, pos, Wp, bp, ei, qbf, kvp, poolP, out);
  }
}